// Round 1
// baseline (444.950 us; speedup 1.0000x reference)
//
#include <hip/hip_runtime.h>

typedef __attribute__((ext_vector_type(4))) float f32x4;
typedef __attribute__((ext_vector_type(8))) short bf16x8;

#define BM 128
#define BN 128
#define BK 64

static __device__ __forceinline__ ushort f2b(float f) {
    uint u = __float_as_uint(f);
    uint r = (u + 0x7fffu + ((u >> 16) & 1u)) >> 16;
    return (ushort)r;
}
static __device__ __forceinline__ float b2f(ushort h) {
    return __uint_as_float(((uint)h) << 16);
}

// ---------------- fp32 -> bf16 convert (vectorized, grid-stride) -------------
__global__ __launch_bounds__(256) void f2b_kernel(const float* __restrict__ in,
                                                  ushort* __restrict__ out, int n4) {
    int i = blockIdx.x * blockDim.x + threadIdx.x;
    int stride = gridDim.x * blockDim.x;
    for (; i < n4; i += stride) {
        float4 v = ((const float4*)in)[i];
        ushort4 o;
        o.x = f2b(v.x); o.y = f2b(v.y); o.z = f2b(v.z); o.w = f2b(v.w);
        ((ushort4*)out)[i] = o;
    }
}

// ---------------- bf16 GEMM, C = A * B^T  (A: MxK, Bw: NxK, C: MxN bf16) ----
// m97 structure: 128x128 tile, BK=64, 4 waves (2x2), 16x16x32 MFMA,
// global_load_lds width-16 staging, 2-barrier K loop.
__global__ __launch_bounds__(256) void gemm_bt(const ushort* __restrict__ A,
                                               const ushort* __restrict__ Bw,
                                               ushort* __restrict__ C,
                                               int M, int N, int K) {
    __shared__ ushort As[BM * BK];
    __shared__ ushort Bs[BN * BK];

    // XCD-chunked swizzle: nwg divisible by 8; XCD c owns a contiguous range of
    // original ids so the 8 column tiles of one row-block run on one XCD (L2 reuse).
    int nwg = gridDim.x;
    int cpx = nwg >> 3;
    int bid = blockIdx.x;
    int orig = (bid & 7) * cpx + (bid >> 3);
    int ctn = N / BN;
    int rt = orig / ctn, ct = orig % ctn;
    int row0 = rt * BM, col0 = ct * BN;

    int t = threadIdx.x;
    int l = t & 63, w = t >> 6;
    int wr = w >> 1, wc = w & 1;
    const int lr = l & 15;
    const int kq = (l >> 4) * 8;

    f32x4 acc[4][4] = {};

    for (int k0 = 0; k0 < K; k0 += BK) {
#pragma unroll
        for (int i = 0; i < 4; ++i) {
            int e = i * 256 + t;      // 16B-chunk index within the 128x64 tile
            int r = e >> 3, c8 = e & 7;
            const ushort* ga = A + (size_t)(row0 + r) * K + k0 + c8 * 8;
            const ushort* gb = Bw + (size_t)(col0 + r) * K + k0 + c8 * 8;
            // wave-uniform LDS base + lane*16 (hardware scatter)
            ushort* la = (ushort*)As + (size_t)(i * 256 + w * 64) * 8;
            ushort* lb = (ushort*)Bs + (size_t)(i * 256 + w * 64) * 8;
            __builtin_amdgcn_global_load_lds(
                (const __attribute__((address_space(1))) void*)ga,
                (__attribute__((address_space(3))) void*)la, 16, 0, 0);
            __builtin_amdgcn_global_load_lds(
                (const __attribute__((address_space(1))) void*)gb,
                (__attribute__((address_space(3))) void*)lb, 16, 0, 0);
        }
        __syncthreads();
#pragma unroll
        for (int kk = 0; kk < BK; kk += 32) {
            bf16x8 a[4], b[4];
#pragma unroll
            for (int m = 0; m < 4; ++m)
                a[m] = *(const bf16x8*)&As[(wr * 64 + m * 16 + lr) * BK + kk + kq];
#pragma unroll
            for (int n = 0; n < 4; ++n)
                b[n] = *(const bf16x8*)&Bs[(wc * 64 + n * 16 + lr) * BK + kk + kq];
#pragma unroll
            for (int m = 0; m < 4; ++m)
#pragma unroll
                for (int n = 0; n < 4; ++n)
                    acc[m][n] = __builtin_amdgcn_mfma_f32_16x16x32_bf16(
                        a[m], b[n], acc[m][n], 0, 0, 0);
        }
        __syncthreads();
    }

    // epilogue: C/D layout col=lane&15, row=(lane>>4)*4+reg
#pragma unroll
    for (int m = 0; m < 4; ++m) {
        int grb = row0 + wr * 64 + m * 16 + (l >> 4) * 4;
#pragma unroll
        for (int n = 0; n < 4; ++n) {
            int gc = col0 + wc * 64 + n * 16 + lr;
#pragma unroll
            for (int j = 0; j < 4; ++j)
                C[(size_t)(grb + j) * N + gc] = f2b(acc[m][n][j]);
        }
    }
}

// ---------------- gf[b,e] = mean_n( l2norm(K_pre)[n,e] * V[n,e] ) -----------
__global__ __launch_bounds__(256) void kv_reduce(const ushort* __restrict__ Kp,
                                                 const ushort* __restrict__ Vp,
                                                 float* __restrict__ gf) {
    const int D = 1024, N = 4096;
    int b = blockIdx.y;
    int r0 = blockIdx.x * 64;
    int t = threadIdx.x, l = t & 63, w = t >> 6;
    __shared__ float red[4];
    float a0 = 0.f, a1 = 0.f, a2 = 0.f, a3 = 0.f;
    for (int r = 0; r < 64; ++r) {
        size_t row = (size_t)b * N + r0 + r;
        ushort4 kv = *(const ushort4*)&Kp[row * D + t * 4];
        ushort4 vv = *(const ushort4*)&Vp[row * D + t * 4];
        float k0 = b2f(kv.x), k1 = b2f(kv.y), k2 = b2f(kv.z), k3 = b2f(kv.w);
        float ss = k0 * k0 + k1 * k1 + k2 * k2 + k3 * k3;
#pragma unroll
        for (int off = 32; off; off >>= 1) ss += __shfl_xor(ss, off);
        if (l == 0) red[w] = ss;
        __syncthreads();
        float tot = red[0] + red[1] + red[2] + red[3];
        __syncthreads();
        float inv = 1.0f / fmaxf(sqrtf(tot), 1e-12f);
        a0 += k0 * inv * b2f(vv.x);
        a1 += k1 * inv * b2f(vv.y);
        a2 += k2 * inv * b2f(vv.z);
        a3 += k3 * inv * b2f(vv.w);
    }
    const float sc = 1.0f / 4096.0f;
    atomicAdd(&gf[b * D + t * 4 + 0], a0 * sc);
    atomicAdd(&gf[b * D + t * 4 + 1], a1 * sc);
    atomicAdd(&gf[b * D + t * 4 + 2], a2 * sc);
    atomicAdd(&gf[b * D + t * 4 + 3], a3 * sc);
}

// ---------------- out[row,e] = l2norm(Q_pre)[row,e] * gf[b,e]  (fp32 out) ---
__global__ __launch_bounds__(256) void q_scale(const ushort* __restrict__ Qp,
                                               const float* __restrict__ gf,
                                               float* __restrict__ out) {
    const int D = 1024;
    int row = blockIdx.x;
    int b = row >> 12;  // N = 4096
    int t = threadIdx.x, l = t & 63, w = t >> 6;
    __shared__ float red[4];
    ushort4 q = *(const ushort4*)&Qp[(size_t)row * D + t * 4];
    float q0 = b2f(q.x), q1 = b2f(q.y), q2 = b2f(q.z), q3 = b2f(q.w);
    float ss = q0 * q0 + q1 * q1 + q2 * q2 + q3 * q3;
#pragma unroll
    for (int off = 32; off; off >>= 1) ss += __shfl_xor(ss, off);
    if (l == 0) red[w] = ss;
    __syncthreads();
    float tot = red[0] + red[1] + red[2] + red[3];
    float inv = 1.0f / fmaxf(sqrtf(tot), 1e-12f);
    float4 g = *(const float4*)&gf[b * D + t * 4];
    float4 o;
    o.x = q0 * inv * g.x;
    o.y = q1 * inv * g.y;
    o.z = q2 * inv * g.z;
    o.w = q3 * inv * g.w;
    *(float4*)&out[(size_t)row * D + t * 4] = o;
}

extern "C" void kernel_launch(void* const* d_in, const int* in_sizes, int n_in,
                              void* d_out, int out_size, void* d_ws, size_t ws_size,
                              hipStream_t stream) {
    const float* x  = (const float*)d_in[0];
    const float* Wq = (const float*)d_in[1];
    const float* Wk = (const float*)d_in[2];
    const float* Wv = (const float*)d_in[3];
    float* out = (float*)d_out;

    const int Bb = 8, Nn = 4096, D = 1024;
    const int M = Bb * Nn;  // 32768 rows

    char* ws = (char*)d_ws;
    ushort* xb  = (ushort*)ws;                         // 67108864 B
    ushort* wqb = (ushort*)(ws + 67108864);            // 2097152 B
    ushort* wkb = (ushort*)(ws + 69206016);            // 2097152 B
    ushort* wvb = (ushort*)(ws + 71303168);            // 2097152 B
    ushort* P1  = (ushort*)(ws + 73400320);            // 67108864 B (Q_pre)
    float*  gf  = (float*)(ws + 140509184);            // 32768 B

    // d_out (134.2 MB) doubles as bf16 scratch for K_pre / V until q_scale.
    ushort* Kp = (ushort*)d_out;
    ushort* Vp = Kp + (size_t)M * D;

    hipMemsetAsync(gf, 0, Bb * D * sizeof(float), stream);

    f2b_kernel<<<2048, 256, 0, stream>>>(x, xb, (M * D) / 4);
    f2b_kernel<<<256, 256, 0, stream>>>(Wq, wqb, (D * D) / 4);
    f2b_kernel<<<256, 256, 0, stream>>>(Wk, wkb, (D * D) / 4);
    f2b_kernel<<<256, 256, 0, stream>>>(Wv, wvb, (D * D) / 4);

    dim3 gg((M / BM) * (D / BN));  // 2048
    gemm_bt<<<gg, 256, 0, stream>>>(xb, wkb, Kp, M, D, D);
    gemm_bt<<<gg, 256, 0, stream>>>(xb, wvb, Vp, M, D, D);
    kv_reduce<<<dim3(64, 8), 256, 0, stream>>>(Kp, Vp, gf);
    gemm_bt<<<gg, 256, 0, stream>>>(xb, wqb, P1, M, D, D);
    q_scale<<<M, 256, 0, stream>>>(P1, gf, out);
}

// Round 2
// 402.503 us; speedup vs baseline: 1.1055x; 1.1055x over previous
//
#include <hip/hip_runtime.h>

typedef __attribute__((ext_vector_type(4))) float f32x4;
typedef __attribute__((ext_vector_type(8))) short bf16x8;

#define BM 256
#define BN 256
#define BK 32
// per-matrix per-tile LDS: 256 rows x 32 cols x 2B = 16384 B = 8192 ushorts

static __device__ __forceinline__ ushort f2b(float f) {
    uint u = __float_as_uint(f);
    uint r = (u + 0x7fffu + ((u >> 16) & 1u)) >> 16;
    return (ushort)r;
}
static __device__ __forceinline__ float b2f(ushort h) {
    return __uint_as_float(((uint)h) << 16);
}

// ---------------- fp32 -> bf16 convert (vectorized, grid-stride) -------------
__global__ __launch_bounds__(256) void f2b_kernel(const float* __restrict__ in,
                                                  ushort* __restrict__ out, int n4) {
    int i = blockIdx.x * blockDim.x + threadIdx.x;
    int stride = gridDim.x * blockDim.x;
    for (; i < n4; i += stride) {
        float4 v = ((const float4*)in)[i];
        ushort4 o;
        o.x = f2b(v.x); o.y = f2b(v.y); o.z = f2b(v.z); o.w = f2b(v.w);
        ((ushort4*)out)[i] = o;
    }
}

// ---------------- bf16 GEMM, C = A * B^T, 256x256 tile, ring-4 pipeline -----
// LDS swizzle g(r,c16) = ((r<<6)|(c16<<4)) ^ ((r&7)<<4)  (bytes within a tile).
// Bijective; 16 lanes reading 16 consecutive rows at fixed c16 hit all 8
// 16B bank-groups (2-way = free). global_load_lds writes LINEAR dest; the
// global SOURCE address is pre-inverse-swizzled (rule #21).
__device__ __forceinline__ void stage_tile(
    const ushort* __restrict__ A, const ushort* __restrict__ Bw,
    ushort* As, ushort* Bs, int tt, int row0, int col0, int K,
    int r0, int c0, int r1, int c1, int w) {
    int buf = tt & 3;
    int k0 = tt * BK;
    ushort* lA0 = As + buf * 8192 + (w << 6) * 8;
    ushort* lA1 = As + buf * 8192 + (512 + (w << 6)) * 8;
    ushort* lB0 = Bs + buf * 8192 + (w << 6) * 8;
    ushort* lB1 = Bs + buf * 8192 + (512 + (w << 6)) * 8;
    const ushort* gA0 = A + (size_t)(row0 + r0) * K + k0 + c0 * 8;
    const ushort* gA1 = A + (size_t)(row0 + r1) * K + k0 + c1 * 8;
    const ushort* gB0 = Bw + (size_t)(col0 + r0) * K + k0 + c0 * 8;
    const ushort* gB1 = Bw + (size_t)(col0 + r1) * K + k0 + c1 * 8;
    __builtin_amdgcn_global_load_lds((const __attribute__((address_space(1))) void*)gA0,
                                     (__attribute__((address_space(3))) void*)lA0, 16, 0, 0);
    __builtin_amdgcn_global_load_lds((const __attribute__((address_space(1))) void*)gA1,
                                     (__attribute__((address_space(3))) void*)lA1, 16, 0, 0);
    __builtin_amdgcn_global_load_lds((const __attribute__((address_space(1))) void*)gB0,
                                     (__attribute__((address_space(3))) void*)lB0, 16, 0, 0);
    __builtin_amdgcn_global_load_lds((const __attribute__((address_space(1))) void*)gB1,
                                     (__attribute__((address_space(3))) void*)lB1, 16, 0, 0);
}

__global__ __launch_bounds__(512, 2) void gemm_bt2(const ushort* __restrict__ A,
                                                   const ushort* __restrict__ Bw,
                                                   ushort* __restrict__ C,
                                                   int M, int N, int K) {
    __shared__ ushort As[4 * 8192];  // 64 KiB
    __shared__ ushort Bs[4 * 8192];  // 64 KiB

    // T1: XCD-chunked swizzle (nwg divisible by 8)
    int nwg = gridDim.x;
    int cpx = nwg >> 3;
    int bid = blockIdx.x;
    int orig = (bid & 7) * cpx + (bid >> 3);
    int ctn = N / BN;
    int rt = orig / ctn, ct = orig % ctn;
    int row0 = rt * BM, col0 = ct * BN;

    int t = threadIdx.x, l = t & 63, w = t >> 6;
    int wr = w >> 2, wc = w & 3;       // wave grid 2 (M) x 4 (N)
    int lr = l & 15, c16 = l >> 4;

    // staging geometry: invert g() for this thread's two 16B chunks
    int r_[2], c_[2];
#pragma unroll
    for (int i = 0; i < 2; ++i) {
        int d = (i * 512 + t) * 16;
        int rr = ((d >> 6) & ~1) | (((d >> 6) ^ (d >> 8)) & 1);
        r_[i] = rr;
        c_[i] = ((d >> 4) & 3) ^ (rr & 3);
    }

    // fragment read bases (byte offsets within one 16 KiB tile)
    int mask = (lr & 7) << 4;
    int baseA = ((((wr * 128 + lr) << 6) | (c16 << 4)) ^ mask);
    int baseB = ((((wc * 64 + lr) << 6) | (c16 << 4)) ^ mask);

    f32x4 acc[8][4] = {};

    int NT = K / BK;  // 32
    stage_tile(A, Bw, As, Bs, 0, row0, col0, K, r_[0], c_[0], r_[1], c_[1], w);
    stage_tile(A, Bw, As, Bs, 1, row0, col0, K, r_[0], c_[0], r_[1], c_[1], w);
    stage_tile(A, Bw, As, Bs, 2, row0, col0, K, r_[0], c_[0], r_[1], c_[1], w);

    for (int tt = 0; tt < NT; ++tt) {
        int ah = NT - 1 - tt;
        if (ah > 2) ah = 2;
        // T4: counted vmcnt — tile tt's 4 loads are older than the newest 4*ah
        if (ah == 2)      asm volatile("s_waitcnt vmcnt(8)" ::: "memory");
        else if (ah == 1) asm volatile("s_waitcnt vmcnt(4)" ::: "memory");
        else              asm volatile("s_waitcnt vmcnt(0)" ::: "memory");
        __builtin_amdgcn_s_barrier();
        // stage tile tt+3 into buf[(tt-1)&3] — safe: all waves' reads of tile
        // tt-1 completed before this barrier (lgkm waits precede their MFMAs)
        if (tt + 3 < NT)
            stage_tile(A, Bw, As, Bs, tt + 3, row0, col0, K, r_[0], c_[0], r_[1], c_[1], w);

        const char* At = (const char*)As + (tt & 3) * 16384;
        const char* Bt = (const char*)Bs + (tt & 3) * 16384;
        bf16x8 a[8], b[4];
#pragma unroll
        for (int m = 0; m < 8; ++m)
            a[m] = *(const bf16x8*)(At + baseA + m * 1024);
#pragma unroll
        for (int n = 0; n < 4; ++n)
            b[n] = *(const bf16x8*)(Bt + baseB + n * 1024);

        __builtin_amdgcn_s_setprio(1);  // T5
#pragma unroll
        for (int m = 0; m < 8; ++m)
#pragma unroll
            for (int n = 0; n < 4; ++n)
                acc[m][n] = __builtin_amdgcn_mfma_f32_16x16x32_bf16(a[m], b[n], acc[m][n], 0, 0, 0);
        __builtin_amdgcn_s_setprio(0);
    }

    // epilogue: C/D layout col=lane&15, row=(lane>>4)*4+reg
#pragma unroll
    for (int m = 0; m < 8; ++m) {
        int gr = row0 + wr * 128 + m * 16 + c16 * 4;
#pragma unroll
        for (int n = 0; n < 4; ++n) {
            int gc = col0 + wc * 64 + n * 16 + lr;
#pragma unroll
            for (int j = 0; j < 4; ++j)
                C[(size_t)(gr + j) * N + gc] = f2b(acc[m][n][j]);
        }
    }
}

// ---------------- gf[b,e] = mean_n( l2norm(K_pre)[n,e] * V[n,e] ) -----------
__global__ __launch_bounds__(256) void kv_reduce(const ushort* __restrict__ Kp,
                                                 const ushort* __restrict__ Vp,
                                                 float* __restrict__ gf) {
    const int D = 1024, N = 4096;
    int b = blockIdx.y;
    int r0 = blockIdx.x * 64;
    int t = threadIdx.x, l = t & 63, w = t >> 6;
    __shared__ float red[4];
    float a0 = 0.f, a1 = 0.f, a2 = 0.f, a3 = 0.f;
    for (int r = 0; r < 64; ++r) {
        size_t row = (size_t)b * N + r0 + r;
        ushort4 kv = *(const ushort4*)&Kp[row * D + t * 4];
        ushort4 vv = *(const ushort4*)&Vp[row * D + t * 4];
        float k0 = b2f(kv.x), k1 = b2f(kv.y), k2 = b2f(kv.z), k3 = b2f(kv.w);
        float ss = k0 * k0 + k1 * k1 + k2 * k2 + k3 * k3;
#pragma unroll
        for (int off = 32; off; off >>= 1) ss += __shfl_xor(ss, off);
        if (l == 0) red[w] = ss;
        __syncthreads();
        float tot = red[0] + red[1] + red[2] + red[3];
        __syncthreads();
        float inv = 1.0f / fmaxf(sqrtf(tot), 1e-12f);
        a0 += k0 * inv * b2f(vv.x);
        a1 += k1 * inv * b2f(vv.y);
        a2 += k2 * inv * b2f(vv.z);
        a3 += k3 * inv * b2f(vv.w);
    }
    const float sc = 1.0f / 4096.0f;
    atomicAdd(&gf[b * D + t * 4 + 0], a0 * sc);
    atomicAdd(&gf[b * D + t * 4 + 1], a1 * sc);
    atomicAdd(&gf[b * D + t * 4 + 2], a2 * sc);
    atomicAdd(&gf[b * D + t * 4 + 3], a3 * sc);
}

// ---------------- out[row,e] = l2norm(Q_pre)[row,e] * gf[b,e]  (fp32 out) ---
__global__ __launch_bounds__(256) void q_scale(const ushort* __restrict__ Qp,
                                               const float* __restrict__ gf,
                                               float* __restrict__ out) {
    const int D = 1024;
    int row = blockIdx.x;
    int b = row >> 12;  // N = 4096
    int t = threadIdx.x, l = t & 63, w = t >> 6;
    __shared__ float red[4];
    ushort4 q = *(const ushort4*)&Qp[(size_t)row * D + t * 4];
    float q0 = b2f(q.x), q1 = b2f(q.y), q2 = b2f(q.z), q3 = b2f(q.w);
    float ss = q0 * q0 + q1 * q1 + q2 * q2 + q3 * q3;
#pragma unroll
    for (int off = 32; off; off >>= 1) ss += __shfl_xor(ss, off);
    if (l == 0) red[w] = ss;
    __syncthreads();
    float tot = red[0] + red[1] + red[2] + red[3];
    float inv = 1.0f / fmaxf(sqrtf(tot), 1e-12f);
    float4 g = *(const float4*)&gf[b * D + t * 4];
    float4 o;
    o.x = q0 * inv * g.x;
    o.y = q1 * inv * g.y;
    o.z = q2 * inv * g.z;
    o.w = q3 * inv * g.w;
    *(float4*)&out[(size_t)row * D + t * 4] = o;
}

extern "C" void kernel_launch(void* const* d_in, const int* in_sizes, int n_in,
                              void* d_out, int out_size, void* d_ws, size_t ws_size,
                              hipStream_t stream) {
    const float* x  = (const float*)d_in[0];
    const float* Wq = (const float*)d_in[1];
    const float* Wk = (const float*)d_in[2];
    const float* Wv = (const float*)d_in[3];
    float* out = (float*)d_out;

    const int Bb = 8, Nn = 4096, D = 1024;
    const int M = Bb * Nn;  // 32768 rows

    char* ws = (char*)d_ws;
    ushort* xb  = (ushort*)ws;                         // 67108864 B
    ushort* wqb = (ushort*)(ws + 67108864);            // 2097152 B
    ushort* wkb = (ushort*)(ws + 69206016);            // 2097152 B
    ushort* wvb = (ushort*)(ws + 71303168);            // 2097152 B
    ushort* P1  = (ushort*)(ws + 73400320);            // 67108864 B (Q_pre)
    float*  gf  = (float*)(ws + 140509184);            // 32768 B

    // d_out (134.2 MB) doubles as bf16 scratch for K_pre / V until q_scale.
    ushort* Kp = (ushort*)d_out;
    ushort* Vp = Kp + (size_t)M * D;

    hipMemsetAsync(gf, 0, Bb * D * sizeof(float), stream);

    f2b_kernel<<<2048, 256, 0, stream>>>(x, xb, (M * D) / 4);
    f2b_kernel<<<256, 256, 0, stream>>>(Wq, wqb, (D * D) / 4);
    f2b_kernel<<<256, 256, 0, stream>>>(Wk, wkb, (D * D) / 4);
    f2b_kernel<<<256, 256, 0, stream>>>(Wv, wvb, (D * D) / 4);

    dim3 gg((M / BM) * (D / BN));  // 512
    gemm_bt2<<<gg, 512, 0, stream>>>(xb, wkb, Kp, M, D, D);
    gemm_bt2<<<gg, 512, 0, stream>>>(xb, wvb, Vp, M, D, D);
    kv_reduce<<<dim3(64, 8), 256, 0, stream>>>(Kp, Vp, gf);
    gemm_bt2<<<gg, 512, 0, stream>>>(xb, wqb, P1, M, D, D);
    q_scale<<<M, 256, 0, stream>>>(P1, gf, out);
}

// Round 3
// 340.348 us; speedup vs baseline: 1.3073x; 1.1826x over previous
//
#include <hip/hip_runtime.h>

typedef __attribute__((ext_vector_type(4))) float f32x4;
typedef __attribute__((ext_vector_type(8))) short bf16x8;

#define BM 256
#define BN 256
#define BK 32
// per-matrix per-tile LDS: 256 rows x 32 cols x 2B = 16384 B = 8192 ushorts

static __device__ __forceinline__ ushort f2b(float f) {
    uint u = __float_as_uint(f);
    uint r = (u + 0x7fffu + ((u >> 16) & 1u)) >> 16;
    return (ushort)r;
}
static __device__ __forceinline__ float b2f(ushort h) {
    return __uint_as_float(((uint)h) << 16);
}

// ---------------- fp32 -> bf16 convert (vectorized, grid-stride) -------------
__global__ __launch_bounds__(256) void f2b_kernel(const float* __restrict__ in,
                                                  ushort* __restrict__ out, int n4) {
    int i = blockIdx.x * blockDim.x + threadIdx.x;
    int stride = gridDim.x * blockDim.x;
    for (; i < n4; i += stride) {
        float4 v = ((const float4*)in)[i];
        ushort4 o;
        o.x = f2b(v.x); o.y = f2b(v.y); o.z = f2b(v.z); o.w = f2b(v.w);
        ((ushort4*)out)[i] = o;
    }
}

// ---------------- bf16 GEMM, C = A * B^T, 256x256 tile --------------------
// Ring-4 LDS buffers, stage-ahead 3 K-tiles, 2 phases per K-tile
// (16 MFMA each), counted vmcnt once per K-tile (8 -> 4 -> 0 tail).
// LDS swizzle g(r,c16) = ((r<<6)|(c16<<4)) ^ ((r&7)<<4)  (bytes within tile);
// global_load_lds writes LINEAR dest; SOURCE is pre-inverse-swizzled.
__device__ __forceinline__ void stage_mat(
    const ushort* __restrict__ G, ushort* Ls, int tt, int rc0, int K,
    int r0, int c0, int r1, int c1, int w) {
    int buf = tt & 3;
    int k0 = tt * BK;
    ushort* l0 = Ls + buf * 8192 + (w << 6) * 8;
    ushort* l1 = Ls + buf * 8192 + (512 + (w << 6)) * 8;
    const ushort* g0 = G + (size_t)(rc0 + r0) * K + k0 + c0 * 8;
    const ushort* g1 = G + (size_t)(rc0 + r1) * K + k0 + c1 * 8;
    __builtin_amdgcn_global_load_lds((const __attribute__((address_space(1))) void*)g0,
                                     (__attribute__((address_space(3))) void*)l0, 16, 0, 0);
    __builtin_amdgcn_global_load_lds((const __attribute__((address_space(1))) void*)g1,
                                     (__attribute__((address_space(3))) void*)l1, 16, 0, 0);
}

__global__ __launch_bounds__(512, 2) void gemm_bt2(const ushort* __restrict__ A,
                                                   const ushort* __restrict__ Bw,
                                                   ushort* __restrict__ C,
                                                   int M, int N, int K) {
    __shared__ ushort As[4 * 8192];  // 64 KiB
    __shared__ ushort Bs[4 * 8192];  // 64 KiB

    // T1: XCD-chunked swizzle (nwg divisible by 8)
    int nwg = gridDim.x;
    int cpx = nwg >> 3;
    int bid = blockIdx.x;
    int orig = (bid & 7) * cpx + (bid >> 3);
    int ctn = N / BN;
    int rt = orig / ctn, ct = orig % ctn;
    int row0 = rt * BM, col0 = ct * BN;

    int t = threadIdx.x, l = t & 63, w = t >> 6;
    int wr = w >> 2, wc = w & 3;       // wave grid 2 (M) x 4 (N)
    int lr = l & 15, c16 = l >> 4;

    // staging geometry: invert g() for this thread's two 16B chunks
    int r_[2], c_[2];
#pragma unroll
    for (int i = 0; i < 2; ++i) {
        int d = (i * 512 + t) * 16;
        int rr = ((d >> 6) & ~1) | (((d >> 6) ^ (d >> 8)) & 1);
        r_[i] = rr;
        c_[i] = ((d >> 4) & 3) ^ (rr & 3);
    }

    // fragment read bases (byte offsets within one 16 KiB tile)
    int mask = (lr & 7) << 4;
    int baseA = ((((wr * 128 + lr) << 6) | (c16 << 4)) ^ mask);
    int baseB = ((((wc * 64 + lr) << 6) | (c16 << 4)) ^ mask);

    f32x4 acc[8][4] = {};

    const int NT = 32;  // K=1024 / BK
    stage_mat(A, As, 0, row0, K, r_[0], c_[0], r_[1], c_[1], w);
    stage_mat(Bw, Bs, 0, col0, K, r_[0], c_[0], r_[1], c_[1], w);
    stage_mat(A, As, 1, row0, K, r_[0], c_[0], r_[1], c_[1], w);
    stage_mat(Bw, Bs, 1, col0, K, r_[0], c_[0], r_[1], c_[1], w);
    stage_mat(A, As, 2, row0, K, r_[0], c_[0], r_[1], c_[1], w);
    stage_mat(Bw, Bs, 2, col0, K, r_[0], c_[0], r_[1], c_[1], w);
    asm volatile("s_waitcnt vmcnt(8)" ::: "memory");  // tile 0 landed
    __builtin_amdgcn_s_barrier();

    for (int tt = 0; tt < NT; ++tt) {
        const char* At = (const char*)As + (tt & 3) * 16384;
        const char* Bt = (const char*)Bs + (tt & 3) * 16384;
        bf16x8 a0[4], a1[4], b[4];

        // ---- phase A: read a[0:4], b[0:4]; stage next A; 16 MFMA ----
#pragma unroll
        for (int m = 0; m < 4; ++m)
            a0[m] = *(const bf16x8*)(At + baseA + m * 1024);
#pragma unroll
        for (int n = 0; n < 4; ++n)
            b[n] = *(const bf16x8*)(Bt + baseB + n * 1024);
        if (tt + 3 < NT)
            stage_mat(A, As, tt + 3, row0, K, r_[0], c_[0], r_[1], c_[1], w);
        __builtin_amdgcn_s_barrier();
        __builtin_amdgcn_s_setprio(1);
#pragma unroll
        for (int m = 0; m < 4; ++m)
#pragma unroll
            for (int n = 0; n < 4; ++n)
                acc[m][n] = __builtin_amdgcn_mfma_f32_16x16x32_bf16(a0[m], b[n], acc[m][n], 0, 0, 0);
        __builtin_amdgcn_s_setprio(0);
        __builtin_amdgcn_s_barrier();

        // ---- phase B: read a[4:8]; stage next B; vmcnt; 16 MFMA ----
#pragma unroll
        for (int m = 0; m < 4; ++m)
            a1[m] = *(const bf16x8*)(At + baseA + (m + 4) * 1024);
        if (tt + 3 < NT)
            stage_mat(Bw, Bs, tt + 3, col0, K, r_[0], c_[0], r_[1], c_[1], w);
        // guarantee tile tt+1 landed for next phase A (newer: tiles tt+2,tt+3)
        if (tt <= NT - 4)      asm volatile("s_waitcnt vmcnt(8)" ::: "memory");
        else if (tt == NT - 3) asm volatile("s_waitcnt vmcnt(4)" ::: "memory");
        else if (tt == NT - 2) asm volatile("s_waitcnt vmcnt(0)" ::: "memory");
        __builtin_amdgcn_s_barrier();
        __builtin_amdgcn_s_setprio(1);
#pragma unroll
        for (int m = 0; m < 4; ++m)
#pragma unroll
            for (int n = 0; n < 4; ++n)
                acc[m + 4][n] = __builtin_amdgcn_mfma_f32_16x16x32_bf16(a1[m], b[n], acc[m + 4][n], 0, 0, 0);
        __builtin_amdgcn_s_setprio(0);
        __builtin_amdgcn_s_barrier();
    }

    // epilogue: C/D layout col=lane&15, row=(lane>>4)*4+reg
#pragma unroll
    for (int m = 0; m < 8; ++m) {
        int gr = row0 + wr * 128 + m * 16 + c16 * 4;
#pragma unroll
        for (int n = 0; n < 4; ++n) {
            int gc = col0 + wc * 64 + n * 16 + lr;
#pragma unroll
            for (int j = 0; j < 4; ++j)
                C[(size_t)(gr + j) * N + gc] = f2b(acc[m][n][j]);
        }
    }
}

// ---------------- gf[b,e] = mean_n( l2norm(K_pre)[n,e] * V[n,e] ) -----------
// Wave-local: one row per wave per iteration, no per-row __syncthreads.
// Lane l owns cols {l*8 + i*512 + j : i in 0..1, j in 0..7}.
__global__ __launch_bounds__(256) void kv_reduce(const ushort* __restrict__ Kp,
                                                 const ushort* __restrict__ Vp,
                                                 float* __restrict__ gf) {
    const int D = 1024, N = 4096;
    int b = blockIdx.y;
    int t = threadIdx.x, l = t & 63, w = t >> 6;
    int r0 = blockIdx.x * 128 + w * 32;  // gridDim.x = 32, 4 waves x 32 rows
    __shared__ float part[4][1024];

    float acc[2][8] = {};
    for (int r = 0; r < 32; ++r) {
        size_t row = (size_t)b * N + r0 + r;
        bf16x8 kv0 = *(const bf16x8*)&Kp[row * D + l * 8];
        bf16x8 kv1 = *(const bf16x8*)&Kp[row * D + l * 8 + 512];
        bf16x8 vv0 = *(const bf16x8*)&Vp[row * D + l * 8];
        bf16x8 vv1 = *(const bf16x8*)&Vp[row * D + l * 8 + 512];
        float kf0[8], kf1[8], ss = 0.f;
#pragma unroll
        for (int j = 0; j < 8; ++j) {
            kf0[j] = b2f((ushort)kv0[j]);
            kf1[j] = b2f((ushort)kv1[j]);
            ss += kf0[j] * kf0[j] + kf1[j] * kf1[j];
        }
#pragma unroll
        for (int off = 32; off; off >>= 1) ss += __shfl_xor(ss, off);
        float inv = 1.0f / fmaxf(sqrtf(ss), 1e-12f);
#pragma unroll
        for (int j = 0; j < 8; ++j) {
            acc[0][j] += kf0[j] * inv * b2f((ushort)vv0[j]);
            acc[1][j] += kf1[j] * inv * b2f((ushort)vv1[j]);
        }
    }
#pragma unroll
    for (int i = 0; i < 2; ++i)
#pragma unroll
        for (int j = 0; j < 8; ++j)
            part[w][l * 8 + i * 512 + j] = acc[i][j];
    __syncthreads();
    const float sc = 1.0f / 4096.0f;
#pragma unroll
    for (int i = 0; i < 4; ++i) {
        int c = t * 4 + (i & 3);
        c = t * 4 + i;
        float s = part[0][c] + part[1][c] + part[2][c] + part[3][c];
        atomicAdd(&gf[b * D + c], s * sc);
    }
}

// ---------------- out[row,e] = l2norm(Q_pre)[row,e] * gf[b,e]  (fp32 out) ---
// One row per wave; lane l owns cols {l*4 + i*256 : i in 0..3} (coalesced).
__global__ __launch_bounds__(256) void q_scale(const ushort* __restrict__ Qp,
                                               const float* __restrict__ gf,
                                               float* __restrict__ out) {
    const int D = 1024;
    int row = blockIdx.x * 4 + (threadIdx.x >> 6);
    int l = threadIdx.x & 63;
    int b = row >> 12;  // N = 4096
    const ushort* qr = &Qp[(size_t)row * D];
    float qf[4][4];
    float ss = 0.f;
#pragma unroll
    for (int i = 0; i < 4; ++i) {
        ushort4 q = *(const ushort4*)&qr[l * 4 + i * 256];
        qf[i][0] = b2f(q.x); qf[i][1] = b2f(q.y);
        qf[i][2] = b2f(q.z); qf[i][3] = b2f(q.w);
        ss += qf[i][0] * qf[i][0] + qf[i][1] * qf[i][1] +
              qf[i][2] * qf[i][2] + qf[i][3] * qf[i][3];
    }
#pragma unroll
    for (int off = 32; off; off >>= 1) ss += __shfl_xor(ss, off);
    float inv = 1.0f / fmaxf(sqrtf(ss), 1e-12f);
#pragma unroll
    for (int i = 0; i < 4; ++i) {
        float4 g = *(const float4*)&gf[b * D + l * 4 + i * 256];
        float4 o;
        o.x = qf[i][0] * inv * g.x;
        o.y = qf[i][1] * inv * g.y;
        o.z = qf[i][2] * inv * g.z;
        o.w = qf[i][3] * inv * g.w;
        *(float4*)&out[(size_t)row * D + l * 4 + i * 256] = o;
    }
}

extern "C" void kernel_launch(void* const* d_in, const int* in_sizes, int n_in,
                              void* d_out, int out_size, void* d_ws, size_t ws_size,
                              hipStream_t stream) {
    const float* x  = (const float*)d_in[0];
    const float* Wq = (const float*)d_in[1];
    const float* Wk = (const float*)d_in[2];
    const float* Wv = (const float*)d_in[3];
    float* out = (float*)d_out;

    const int Bb = 8, Nn = 4096, D = 1024;
    const int M = Bb * Nn;  // 32768 rows

    char* ws = (char*)d_ws;
    ushort* xb  = (ushort*)ws;                         // 67108864 B
    ushort* wqb = (ushort*)(ws + 67108864);            // 2097152 B
    ushort* wkb = (ushort*)(ws + 69206016);            // 2097152 B
    ushort* wvb = (ushort*)(ws + 71303168);            // 2097152 B
    ushort* P1  = (ushort*)(ws + 73400320);            // 67108864 B (Q_pre)
    float*  gf  = (float*)(ws + 140509184);            // 32768 B

    // d_out (134.2 MB) doubles as bf16 scratch for K_pre / V until q_scale.
    ushort* Kp = (ushort*)d_out;
    ushort* Vp = Kp + (size_t)M * D;

    hipMemsetAsync(gf, 0, Bb * D * sizeof(float), stream);

    f2b_kernel<<<2048, 256, 0, stream>>>(x, xb, (M * D) / 4);
    f2b_kernel<<<256, 256, 0, stream>>>(Wq, wqb, (D * D) / 4);
    f2b_kernel<<<256, 256, 0, stream>>>(Wk, wkb, (D * D) / 4);
    f2b_kernel<<<256, 256, 0, stream>>>(Wv, wvb, (D * D) / 4);

    dim3 gg((M / BM) * (D / BN));  // 512
    gemm_bt2<<<gg, 512, 0, stream>>>(xb, wkb, Kp, M, D, D);
    gemm_bt2<<<gg, 512, 0, stream>>>(xb, wvb, Vp, M, D, D);
    kv_reduce<<<dim3(32, 8), 256, 0, stream>>>(Kp, Vp, gf);
    gemm_bt2<<<gg, 512, 0, stream>>>(xb, wqb, P1, M, D, D);
    q_scale<<<M / 4, 256, 0, stream>>>(P1, gf, out);
}